// Round 6
// baseline (38.746 us; speedup 1.0000x reference)
//
#include <hip/hip_runtime.h>

#define BB 32
#define RR 56
#define CC 56
#define CHG 64                      // channel float4-groups (256/4)
#define TP 4                        // output pixels per segment (along C)
#define CSEG (CC / TP)              // 14
#define SEGS (BB * RR * CSEG)       // 25088 segments
#define NWAVE 3584                  // 25088 / 7 — exactly 7 segs per wave
#define NBLK (NWAVE / 4)            // 896 blocks, % 8 == 0
#define SPW 7                       // segments per wave

typedef float nf4 __attribute__((ext_vector_type(4)));

// Persistent-wave version: 3584 waves (1 device fill), each owns 7 contiguous
// segments. Taps hoisted out of the segment loop. Output stores non-temporal.
__global__ __launch_bounds__(256, 4) void dwconv3x3_res5(
    const float4* __restrict__ xv,
    const float4* __restrict__ kv,
    float4* __restrict__ ov)
{
    const int bid = (int)blockIdx.x;
    const int swz = (bid & 7) * (NBLK / 8) + (bid >> 3);   // XCD-chunked
    const int w    = swz * 4 + ((int)threadIdx.x >> 6);
    const int lane = (int)threadIdx.x & 63;
    const int seg0 = w * SPW;

    // kernel taps: 3x3 x float4; center (t=4) masked in reference
    float4 kt[9];
    #pragma unroll
    for (int t = 0; t < 9; ++t)
        if (t != 4) kt[t] = kv[t * CHG + lane];

    for (int s = 0; s < SPW; ++s) {
        const int seg = seg0 + s;

        const int b   = seg / (RR * CSEG);
        const int rem = seg - b * (RR * CSEG);
        const int r   = rem / CSEG;
        const int cs  = rem - r * CSEG;
        const int c0  = cs * TP;

        float4 row[3][TP + 2];
        const int pixbase = (b * RR + r) * CC + c0;

        const bool interior = (r > 0) & (r < RR - 1) & (cs > 0) & (cs < CSEG - 1);
        if (interior) {
            // wave-uniform branch (r, cs identical across lanes)
            #pragma unroll
            for (int dr = 0; dr < 3; ++dr) {
                const int rowbase = (pixbase + (dr - 1) * CC - 1) * CHG + lane;
                #pragma unroll
                for (int j = 0; j < TP + 2; ++j)
                    row[dr][j] = xv[rowbase + j * CHG];
            }
        } else {
            #pragma unroll
            for (int dr = 0; dr < 3; ++dr) {
                const int rr2 = r + dr - 1;
                #pragma unroll
                for (int j = 0; j < TP + 2; ++j) {
                    const int cc2 = c0 + j - 1;
                    float4 v = make_float4(0.f, 0.f, 0.f, 0.f);
                    if (rr2 >= 0 && rr2 < RR && cc2 >= 0 && cc2 < CC)
                        v = xv[((b * RR + rr2) * CC + cc2) * CHG + lane];
                    row[dr][j] = v;
                }
            }
        }

        #pragma unroll
        for (int p = 0; p < TP; ++p) {
            float4 acc = row[1][p + 1];   // residual (center tap zeroed)
            #pragma unroll
            for (int dr = 0; dr < 3; ++dr) {
                #pragma unroll
                for (int dc = 0; dc < 3; ++dc) {
                    if (dr == 1 && dc == 1) continue;
                    const float4 kk = kt[dr * 3 + dc];
                    const float4 xx = row[dr][p + dc];
                    acc.x += kk.x * xx.x;
                    acc.y += kk.y * xx.y;
                    acc.z += kk.z * xx.z;
                    acc.w += kk.w * xx.w;
                }
            }
            nf4 accv = { acc.x, acc.y, acc.z, acc.w };
            __builtin_nontemporal_store(accv, (nf4*)&ov[(pixbase + p) * CHG + lane]);
        }
    }
}

extern "C" void kernel_launch(void* const* d_in, const int* in_sizes, int n_in,
                              void* d_out, int out_size, void* d_ws, size_t ws_size,
                              hipStream_t stream)
{
    const float4* xv = (const float4*)d_in[0];
    const float4* kv = (const float4*)d_in[1];
    float4* ov       = (float4*)d_out;

    dwconv3x3_res5<<<NBLK, 256, 0, stream>>>(xv, kv, ov);
}